// Round 16
// baseline (162.735 us; speedup 1.0000x reference)
//
#include <hip/hip_runtime.h>
#include <hip/hip_bf16.h>

// B=8, S=2048, D=512. 4 launches:
//   cvt(x,W) -> proj_fused (qk_proj WGs + vt WGs interleaved in ONE grid) ->
//   qk (128x128, BK=32 2-phase dbuf 32KB, packed lower-tri P=exp + row sums)
//   -> pv (complement-paired, 2-phase, 1/l, fp32 out).
// 16x16x32 bf16 MFMA, global_load_lds width-16, XCD batch-pinning (b=wgid&7).
// Round 16: qk_proj (512 WGs, 16-step) and vt_gemm (512 WGs, 8-step) are
// independent after cvt -- merged into one 1024-WG launch, interleaved by
// wg&1 so each CU hosts mixed-phase blocks (latency overlap) and the two
// grid ramp tails collapse into one. Bodies verbatim from r15; qk_proj path
// views the shared 64KB LDS as [2][3][128][32] (48KB).
//
// ws layout (peak 55,050,240 B < 68,681,728 proven):
//   vtb     @ 0          : V^T bf16 [512][16384]
//   partial @ 16777216   : fp32 [16384][16] per-(row, jt-tile) P sums
//   Spacked @ 17825792   : P bf16, 8 x 136 tiles x 128x128 (35,651,584)
//   xb      @ 17825792   : x bf16 (OVERLAPS Spacked; dead before qk writes)
//   wb      @ 53477376   : Wq/Wk/Wv bf16 (3 x 524288)
// d_out scratch: Q bf16 @ 0, K bf16 @ 16777216 (dead before pv overwrites).

typedef __attribute__((ext_vector_type(8))) short short8;
typedef __attribute__((ext_vector_type(4))) float f32x4;

#define S_    2048
#define DM    512
#define SCALE 0.04419417382415922f   // 1/sqrt(512)

static __device__ __forceinline__ unsigned short f2bf(float f) {
    __hip_bfloat16 h = __float2bfloat16(f);
    unsigned short u;
    __builtin_memcpy(&u, &h, sizeof(u));
    return u;
}
static __device__ __forceinline__ float bf2f(unsigned short u) {
    union { unsigned int i; float f; } c;
    c.i = ((unsigned int)u) << 16;
    return c.f;
}

static __device__ __forceinline__ void gload16(const void* g, void* l) {
    __builtin_amdgcn_global_load_lds(
        (const __attribute__((address_space(1))) void*)g,
        (__attribute__((address_space(3))) void*)l, 16, 0, 0);
}

// Stage a 128x64-short tile (row stride ld shorts) into linear LDS [128][64].
static __device__ __forceinline__ void stage_tile(
    const unsigned short* __restrict__ gbase, size_t ld,
    unsigned short (*lds)[64], int w, int lane)
{
    const int srow = lane >> 3;
    const int scol = (lane & 7) * 8;
    #pragma unroll
    for (int t = 0; t < 4; t++) {
        const int row = w * 32 + t * 8 + srow;
        gload16(gbase + (size_t)row * ld + scol, &lds[w * 32 + t * 8][0]);
    }
}

// Stage a 128x32-short tile into linear LDS [128][32] (2 gload_lds per wave).
static __device__ __forceinline__ void stage32(
    const unsigned short* __restrict__ gbase, size_t ld,
    unsigned short (*lds)[32], int w, int lane)
{
    const int srow = lane >> 2;
    const int scol = (lane & 3) * 8;
    #pragma unroll
    for (int t = 0; t < 2; t++) {
        const int row = w * 32 + t * 16 + srow;
        gload16(gbase + (size_t)row * ld + scol, &lds[w * 32 + t * 16][0]);
    }
}

// Compute one BK=64 step from staged A/B tiles.
static __device__ __forceinline__ void mfma_step(
    const unsigned short (*Ash)[64], const unsigned short (*Bsh)[64],
    f32x4 acc[4][4], int wm, int wn, int lr, int lg)
{
    #pragma unroll
    for (int kk = 0; kk < 2; kk++) {
        short8 af[4], bf[4];
        #pragma unroll
        for (int m = 0; m < 4; m++)
            af[m] = *reinterpret_cast<const short8*>(&Ash[wm * 64 + m * 16 + lr][kk * 32 + lg * 8]);
        #pragma unroll
        for (int n = 0; n < 4; n++)
            bf[n] = *reinterpret_cast<const short8*>(&Bsh[wn * 64 + n * 16 + lr][kk * 32 + lg * 8]);
        #pragma unroll
        for (int m = 0; m < 4; m++)
            #pragma unroll
            for (int n = 0; n < 4; n++)
                acc[m][n] = __builtin_amdgcn_mfma_f32_16x16x32_bf16(af[m], bf[n], acc[m][n], 0, 0, 0);
    }
}

// Converts x (8192 blocks) and Wq/Wk/Wv (256 blocks each) fp32->bf16.
__global__ __launch_bounds__(256) void cvt_all(
    const float* __restrict__ x,
    const float* __restrict__ wq, const float* __restrict__ wk, const float* __restrict__ wv,
    unsigned short* __restrict__ xb,
    unsigned short* __restrict__ wqb, unsigned short* __restrict__ wkb,
    unsigned short* __restrict__ wvb)
{
    const int bid = blockIdx.x;
    const float* src; unsigned short* dst; int i;
    if (bid < 8192) { src = x; dst = xb; i = bid * 256 + threadIdx.x; }
    else {
        const int r = bid - 8192;
        const int m = r >> 8;
        src = (m == 0) ? wq : (m == 1) ? wk : wv;
        dst = (m == 0) ? wqb : (m == 1) ? wkb : wvb;
        i = (r & 255) * 256 + threadIdx.x;
    }
    float4 v = reinterpret_cast<const float4*>(src)[i];
    ushort4 o;
    o.x = f2bf(v.x); o.y = f2bf(v.y); o.z = f2bf(v.z); o.w = f2bf(v.w);
    reinterpret_cast<ushort4*>(dst)[i] = o;
}

// Merged projections, 1024 WGs interleaved by wg&1:
//   type 0 (idx 0..511): Q = x Wq^T + bq; K = x Wk^T + bk  (BK=32, X once)
//   type 1 (idx 0..511): VT = Wv x^T + bv(per row)         (BK=64)
__global__ __launch_bounds__(256) void proj_fused(
    const unsigned short* __restrict__ X,
    const unsigned short* __restrict__ Wqb, const unsigned short* __restrict__ Wkb,
    const unsigned short* __restrict__ Wvb,
    const float* __restrict__ bq, const float* __restrict__ bk,
    const float* __restrict__ bv,
    unsigned short* __restrict__ Dq, unsigned short* __restrict__ Dk,
    unsigned short* __restrict__ Dvt)
{
    __shared__ unsigned short smem[2][2][128][64];   // 64 KB shared by both paths

    const int wg   = blockIdx.x;
    const int type = wg & 1;
    const int idx  = wg >> 1;

    const int tid  = threadIdx.x;
    const int lane = tid & 63;
    const int w    = tid >> 6;
    const int wm   = w >> 1, wn = w & 1;
    const int lr   = lane & 15, lg = lane >> 4;

    if (type == 0) {
        // ---------------- qk_proj path (48 KB view of smem) ----------------
        unsigned short (*sp)[3][128][32] =
            reinterpret_cast<unsigned short (*)[3][128][32]>(&smem[0][0][0][0]);
        const int m0 = (idx & 127) * 128;
        const int n0 = (idx >> 7) * 128;

        f32x4 accq[4][4], acck[4][4];
        #pragma unroll
        for (int m = 0; m < 4; m++)
            #pragma unroll
            for (int n = 0; n < 4; n++) {
                accq[m][n] = (f32x4){0.f, 0.f, 0.f, 0.f};
                acck[m][n] = (f32x4){0.f, 0.f, 0.f, 0.f};
            }

        stage32(&X[(size_t)m0 * DM], DM, sp[0][0], w, lane);
        stage32(&Wqb[(size_t)n0 * DM], DM, sp[0][1], w, lane);
        stage32(&Wkb[(size_t)n0 * DM], DM, sp[0][2], w, lane);
        __syncthreads();
        int cur = 0;
        for (int t = 0; t < 16; t++) {
            if (t < 15) {
                const int k0 = (t + 1) * 32;
                stage32(&X[(size_t)m0 * DM + k0], DM, sp[cur ^ 1][0], w, lane);
                stage32(&Wqb[(size_t)n0 * DM + k0], DM, sp[cur ^ 1][1], w, lane);
                stage32(&Wkb[(size_t)n0 * DM + k0], DM, sp[cur ^ 1][2], w, lane);
            }
            short8 af[4], bqf[4], bkf[4];
            #pragma unroll
            for (int m = 0; m < 4; m++)
                af[m] = *reinterpret_cast<const short8*>(&sp[cur][0][wm * 64 + m * 16 + lr][lg * 8]);
            #pragma unroll
            for (int n = 0; n < 4; n++) {
                bqf[n] = *reinterpret_cast<const short8*>(&sp[cur][1][wn * 64 + n * 16 + lr][lg * 8]);
                bkf[n] = *reinterpret_cast<const short8*>(&sp[cur][2][wn * 64 + n * 16 + lr][lg * 8]);
            }
            #pragma unroll
            for (int m = 0; m < 4; m++)
                #pragma unroll
                for (int n = 0; n < 4; n++) {
                    accq[m][n] = __builtin_amdgcn_mfma_f32_16x16x32_bf16(af[m], bqf[n], accq[m][n], 0, 0, 0);
                    acck[m][n] = __builtin_amdgcn_mfma_f32_16x16x32_bf16(af[m], bkf[n], acck[m][n], 0, 0, 0);
                }
            __syncthreads();
            cur ^= 1;
        }

        unsigned short (*Csh)[128] = reinterpret_cast<unsigned short (*)[128]>(&smem[0][0][0][0]);
        #pragma unroll
        for (int n = 0; n < 4; n++) {
            int ct = wn * 64 + n * 16 + lr;
            float bcol = bq[n0 + ct];
            #pragma unroll
            for (int m = 0; m < 4; m++) {
                int rt = wm * 64 + m * 16 + lg * 4;
                #pragma unroll
                for (int j = 0; j < 4; j++) {
                    int row = rt + j;
                    Csh[row][ct ^ ((row & 7) << 3)] = f2bf(accq[m][n][j] + bcol);
                }
            }
        }
        __syncthreads();
        #pragma unroll
        for (int i = 0; i < 8; i++) {
            int chunk = i * 256 + tid;
            int row = chunk >> 4, cb = (chunk & 15) * 8;
            short8 vv = *reinterpret_cast<const short8*>(&Csh[row][cb ^ ((row & 7) << 3)]);
            *reinterpret_cast<short8*>(&Dq[(size_t)(m0 + row) * DM + n0 + cb]) = vv;
        }
        __syncthreads();
        #pragma unroll
        for (int n = 0; n < 4; n++) {
            int ct = wn * 64 + n * 16 + lr;
            float bcol = bk[n0 + ct];
            #pragma unroll
            for (int m = 0; m < 4; m++) {
                int rt = wm * 64 + m * 16 + lg * 4;
                #pragma unroll
                for (int j = 0; j < 4; j++) {
                    int row = rt + j;
                    Csh[row][ct ^ ((row & 7) << 3)] = f2bf(acck[m][n][j] + bcol);
                }
            }
        }
        __syncthreads();
        #pragma unroll
        for (int i = 0; i < 8; i++) {
            int chunk = i * 256 + tid;
            int row = chunk >> 4, cb = (chunk & 15) * 8;
            short8 vv = *reinterpret_cast<const short8*>(&Csh[row][cb ^ ((row & 7) << 3)]);
            *reinterpret_cast<short8*>(&Dk[(size_t)(m0 + row) * DM + n0 + cb]) = vv;
        }
    } else {
        // ---------------- vt path (full 64 KB smem) ----------------
        const int n0 = (idx & 127) * 128;     // over 16384 tokens
        const int m0 = (idx >> 7) * 128;      // over DM=512

        f32x4 acc[4][4];
        #pragma unroll
        for (int m = 0; m < 4; m++)
            #pragma unroll
            for (int n = 0; n < 4; n++) acc[m][n] = (f32x4){0.f, 0.f, 0.f, 0.f};

        stage_tile(&Wvb[(size_t)m0 * DM], DM, smem[0][0], w, lane);
        stage_tile(&X[(size_t)n0 * DM], DM, smem[0][1], w, lane);
        __syncthreads();
        int cur = 0;
        for (int t = 0; t < 8; t++) {
            if (t < 7) {
                const int k0 = (t + 1) * 64;
                stage_tile(&Wvb[(size_t)m0 * DM + k0], DM, smem[cur ^ 1][0], w, lane);
                stage_tile(&X[(size_t)n0 * DM + k0], DM, smem[cur ^ 1][1], w, lane);
            }
            mfma_step(smem[cur][0], smem[cur][1], acc, wm, wn, lr, lg);
            __syncthreads();
            cur ^= 1;
        }

        unsigned short (*Csh)[128] = reinterpret_cast<unsigned short (*)[128]>(&smem[0][0][0][0]);
        #pragma unroll
        for (int n = 0; n < 4; n++) {
            int ct = wn * 64 + n * 16 + lr;
            #pragma unroll
            for (int m = 0; m < 4; m++) {
                int rt = wm * 64 + m * 16 + lg * 4;
                #pragma unroll
                for (int j = 0; j < 4; j++) {
                    int row = rt + j;
                    Csh[row][ct ^ ((row & 7) << 3)] = f2bf(acc[m][n][j] + bv[m0 + row]);
                }
            }
        }
        __syncthreads();
        #pragma unroll
        for (int i = 0; i < 8; i++) {
            int chunk = i * 256 + tid;
            int row = chunk >> 4, cb = (chunk & 15) * 8;
            short8 vv = *reinterpret_cast<const short8*>(&Csh[row][cb ^ ((row & 7) << 3)]);
            *reinterpret_cast<short8*>(&Dvt[(size_t)(m0 + row) * 16384 + n0 + cb]) = vv;
        }
    }
}

// P tiles, exact lower triangle, all 8 batches. 1-D grid 1088:
// b = wgid & 7 (XCD-pinned batch), l = wgid >> 3.
// BK=32 2-phase dbuf, 32KB LDS -> high co-residency (r15: 40.4us, 463 TF).
__global__ __launch_bounds__(256) void qk_gemm(
    const unsigned short* __restrict__ Qg, const unsigned short* __restrict__ Kg,
    const unsigned char* __restrict__ pad, unsigned short* __restrict__ Sp,
    float* __restrict__ partial)
{
    __shared__ unsigned short smem[2][2][128][32];   // 32 KB

    const int wgid = blockIdx.x;
    const int b = wgid & 7;
    const int l = wgid >> 3;
    int it = (int)((sqrtf(8.f * l + 1.f) - 1.f) * 0.5f);
    while ((it + 1) * (it + 2) / 2 <= l) ++it;
    while (it * (it + 1) / 2 > l) --it;
    const int jt = l - it * (it + 1) / 2;

    const unsigned short* __restrict__ A = Qg + (size_t)b * S_ * DM;
    const unsigned short* __restrict__ B = Kg + (size_t)b * S_ * DM;
    unsigned short* __restrict__ Sw = Sp + ((size_t)b * 136 + l) * 16384;
    const int m0 = it * 128, n0 = jt * 128;

    const int tid  = threadIdx.x;
    const int lane = tid & 63;
    const int w    = tid >> 6;
    const int wm   = w >> 1, wn = w & 1;
    const int lr   = lane & 15, lg = lane >> 4;

    f32x4 acc[4][4];
    #pragma unroll
    for (int m = 0; m < 4; m++)
        #pragma unroll
        for (int n = 0; n < 4; n++) acc[m][n] = (f32x4){0.f, 0.f, 0.f, 0.f};

    stage32(&A[(size_t)m0 * DM], DM, smem[0][0], w, lane);
    stage32(&B[(size_t)n0 * DM], DM, smem[0][1], w, lane);
    __syncthreads();
    int cur = 0;
    for (int t = 0; t < 16; t++) {
        if (t < 15) {
            const int k0 = (t + 1) * 32;
            stage32(&A[(size_t)m0 * DM + k0], DM, smem[cur ^ 1][0], w, lane);
            stage32(&B[(size_t)n0 * DM + k0], DM, smem[cur ^ 1][1], w, lane);
        }
        short8 af[4], bf[4];
        #pragma unroll
        for (int m = 0; m < 4; m++)
            af[m] = *reinterpret_cast<const short8*>(&smem[cur][0][wm * 64 + m * 16 + lr][lg * 8]);
        #pragma unroll
        for (int n = 0; n < 4; n++)
            bf[n] = *reinterpret_cast<const short8*>(&smem[cur][1][wn * 64 + n * 16 + lr][lg * 8]);
        #pragma unroll
        for (int m = 0; m < 4; m++)
            #pragma unroll
            for (int n = 0; n < 4; n++)
                acc[m][n] = __builtin_amdgcn_mfma_f32_16x16x32_bf16(af[m], bf[n], acc[m][n], 0, 0, 0);
        __syncthreads();
        cur ^= 1;
    }

    // epilogue: P = exp(s*scale) (masked -> 0), repack via 32KB Csh view,
    // 16B/lane stores + per-(row,jt) partial sums.
    unsigned short (*Csh)[128] = reinterpret_cast<unsigned short (*)[128]>(&smem[0][0][0][0]);
    #pragma unroll
    for (int n = 0; n < 4; n++) {
        int ct = wn * 64 + n * 16 + lr;
        int colg = n0 + ct;
        bool pd = pad[(size_t)b * S_ + colg] != 0;
        #pragma unroll
        for (int m = 0; m < 4; m++) {
            int rt = wm * 64 + m * 16 + lg * 4;
            #pragma unroll
            for (int j = 0; j < 4; j++) {
                int row = rt + j;
                float p = (pd || colg > m0 + row) ? 0.f : __expf(acc[m][n][j] * SCALE);
                Csh[row][ct ^ ((row & 7) << 3)] = f2bf(p);
            }
        }
    }
    __syncthreads();
    #pragma unroll
    for (int i = 0; i < 8; i++) {
        int chunk = i * 256 + tid;
        int row = chunk >> 4, cb = (chunk & 15) * 8;
        short8 vv = *reinterpret_cast<const short8*>(&Csh[row][cb ^ ((row & 7) << 3)]);
        *reinterpret_cast<short8*>(&Sw[(size_t)row * 128 + cb]) = vv;
        float s = 0.f;
        #pragma unroll
        for (int e = 0; e < 8; e++) s += bf2f((unsigned short)vv[e]);
        #pragma unroll
        for (int msk = 1; msk < 16; msk <<= 1) s += __shfl_xor(s, msk);
        if ((lane & 15) == 0)
            partial[((size_t)b * S_ + m0 + row) * 16 + jt] = s;
    }
}

// O[q][d] = (sum_{k<kmax} P[q][k] * VT[d][b*2048+k]) / l[q], fp32 out.
// 1-D grid 512: b = wgid & 7 (XCD-pinned), r = wgid >> 3 in [0,64).
// Complementary pairing: it = (r<32) ? 15-(r>>2) : (r>>2)-8; nb = r & 3.
__global__ __launch_bounds__(256) void pv_gemm(
    const unsigned short* __restrict__ Sp, const unsigned short* __restrict__ VT,
    const float* __restrict__ partial, float* __restrict__ Out)
{
    __shared__ unsigned short smem[2][2][128][64];

    const int wgid = blockIdx.x;
    const int b  = wgid & 7;
    const int r  = wgid >> 3;
    const int it = (r < 32) ? (15 - (r >> 2)) : ((r >> 2) - 8);
    const int nb = r & 3;
    const int m0 = it * 128, n0 = nb * 128;
    const int nt = (it + 1) * 2;              // BK=64 steps
    const unsigned short* __restrict__ Abase =
        Sp + ((size_t)b * 136 + (size_t)it * (it + 1) / 2) * 16384;

    const int tid  = threadIdx.x;
    const int lane = tid & 63;
    const int w    = tid >> 6;
    const int wm   = w >> 1, wn = w & 1;
    const int lr   = lane & 15, lg = lane >> 4;

    f32x4 acc[4][4];
    #pragma unroll
    for (int m = 0; m < 4; m++)
        #pragma unroll
        for (int n = 0; n < 4; n++) acc[m][n] = (f32x4){0.f, 0.f, 0.f, 0.f};

    stage_tile(Abase, 128, smem[0][0], w, lane);
    stage_tile(&VT[(size_t)n0 * 16384 + (size_t)b * S_], 16384, smem[0][1], w, lane);
    __syncthreads();
    int cur = 0;
    for (int t = 0; t < nt; t++) {
        if (t + 1 < nt) {
            const int k0 = (t + 1) * 64;
            stage_tile(Abase + (size_t)(k0 >> 7) * 16384 + (k0 & 127), 128, smem[cur ^ 1][0], w, lane);
            stage_tile(&VT[(size_t)n0 * 16384 + (size_t)b * S_ + k0], 16384, smem[cur ^ 1][1], w, lane);
        }
        mfma_step(smem[cur][0], smem[cur][1], acc, wm, wn, lr, lg);
        __syncthreads();
        cur ^= 1;
    }

    // per-row 1/l into LDS (threads 0..127), then normalize + store
    float* Lsh = reinterpret_cast<float*>(&smem[0][0][0][0]);
    if (tid < 128) {
        const float* pr = &partial[((size_t)b * S_ + m0 + tid) * 16];
        float s = 0.f;
        for (int j = 0; j <= it; j++) s += pr[j];
        Lsh[tid] = 1.f / s;
    }
    __syncthreads();

    #pragma unroll
    for (int n = 0; n < 4; n++) {
        int col = n0 + wn * 64 + n * 16 + lr;
        #pragma unroll
        for (int m = 0; m < 4; m++) {
            int rowb = wm * 64 + m * 16 + lg * 4;
            #pragma unroll
            for (int j = 0; j < 4; j++) {
                int row = rowb + j;
                float li = Lsh[row];
                Out[((size_t)(b * S_ + m0 + row)) * DM + col] = acc[m][n][j] * li;
            }
        }
    }
}

extern "C" void kernel_launch(void* const* d_in, const int* in_sizes, int n_in,
                              void* d_out, int out_size, void* d_ws, size_t ws_size,
                              hipStream_t stream) {
    const float* x  = (const float*)d_in[0];
    const unsigned char* pad = (const unsigned char*)d_in[1];
    const float* Wq = (const float*)d_in[2];
    const float* bq = (const float*)d_in[3];
    const float* Wk = (const float*)d_in[4];
    const float* bk = (const float*)d_in[5];
    const float* Wv = (const float*)d_in[6];
    const float* bv = (const float*)d_in[7];
    float* out = (float*)d_out;

    char* ws = (char*)d_ws;
    unsigned short* vtb     = (unsigned short*)(ws);
    float*          partial = (float*)(ws + 16777216);
    unsigned short* Spacked = (unsigned short*)(ws + 17825792);
    unsigned short* xb      = (unsigned short*)(ws + 17825792);  // overlaps Spacked
    unsigned short* wqb     = (unsigned short*)(ws + 53477376);
    unsigned short* wkb     = wqb + 262144;
    unsigned short* wvb     = wqb + 524288;

    // Q,K bf16 scratch in d_out (2 x 16,777,216 B; dead before pv writes)
    unsigned short* qb = (unsigned short*)d_out;
    unsigned short* kb = qb + 8388608;

    cvt_all<<<8960, 256, 0, stream>>>(x, Wq, Wk, Wv, xb, wqb, wkb, wvb);

    proj_fused<<<1024, 256, 0, stream>>>(xb, wqb, wkb, wvb, bq, bk, bv, qb, kb, vtb);

    qk_gemm<<<1088, 256, 0, stream>>>(qb, kb, pad, Spacked, partial);

    pv_gemm<<<512, 256, 0, stream>>>(Spacked, vtb, partial, out);
}

// Round 17
// 127.417 us; speedup vs baseline: 1.2772x; 1.2772x over previous
//
#include <hip/hip_runtime.h>
#include <hip/hip_bf16.h>

// B=8, S=2048, D=512. 5 launches (r15 config + pv BK=32):
//   cvt(x,W) -> qk_proj (fused Q&K projection, BK=32) -> vt_gemm (V^T) ->
//   qk (128x128, BK=32 2-phase dbuf 32KB, packed lower-tri P=exp + row sums)
//   -> pv (complement-paired, BK=32 2-phase dbuf 32KB, 1/l, fp32 out).
// 16x16x32 bf16 MFMA, global_load_lds width-16, XCD batch-pinning (b=wgid&7).
// Round 17: revert r16's proj_fused (co-compiled paths -> 188 VGPR -> 7.7%
// occupancy, -40us). Apply r15's proven BK=32 transform to pv: LDS 64->32KB,
// VGPR ~88->68, 2->4-5 blocks/CU (same mechanism that won +4us on qk).
//
// ws layout (peak 55,050,240 B < 68,681,728 proven):
//   vtb     @ 0          : V^T bf16 [512][16384]
//   partial @ 16777216   : fp32 [16384][16] per-(row, jt-tile) P sums
//   Spacked @ 17825792   : P bf16, 8 x 136 tiles x 128x128 (35,651,584)
//   xb      @ 17825792   : x bf16 (OVERLAPS Spacked; dead before qk writes)
//   wb      @ 53477376   : Wq/Wk/Wv bf16 (3 x 524288)
// d_out scratch: Q bf16 @ 0, K bf16 @ 16777216 (dead before pv overwrites).

typedef __attribute__((ext_vector_type(8))) short short8;
typedef __attribute__((ext_vector_type(4))) float f32x4;

#define S_    2048
#define DM    512
#define SCALE 0.04419417382415922f   // 1/sqrt(512)

static __device__ __forceinline__ unsigned short f2bf(float f) {
    __hip_bfloat16 h = __float2bfloat16(f);
    unsigned short u;
    __builtin_memcpy(&u, &h, sizeof(u));
    return u;
}
static __device__ __forceinline__ float bf2f(unsigned short u) {
    union { unsigned int i; float f; } c;
    c.i = ((unsigned int)u) << 16;
    return c.f;
}

static __device__ __forceinline__ void gload16(const void* g, void* l) {
    __builtin_amdgcn_global_load_lds(
        (const __attribute__((address_space(1))) void*)g,
        (__attribute__((address_space(3))) void*)l, 16, 0, 0);
}

// Stage a 128x64-short tile (row stride ld shorts) into linear LDS [128][64].
static __device__ __forceinline__ void stage_tile(
    const unsigned short* __restrict__ gbase, size_t ld,
    unsigned short (*lds)[64], int w, int lane)
{
    const int srow = lane >> 3;
    const int scol = (lane & 7) * 8;
    #pragma unroll
    for (int t = 0; t < 4; t++) {
        const int row = w * 32 + t * 8 + srow;
        gload16(gbase + (size_t)row * ld + scol, &lds[w * 32 + t * 8][0]);
    }
}

// Stage a 128x32-short tile into linear LDS [128][32] (2 gload_lds per wave).
static __device__ __forceinline__ void stage32(
    const unsigned short* __restrict__ gbase, size_t ld,
    unsigned short (*lds)[32], int w, int lane)
{
    const int srow = lane >> 2;
    const int scol = (lane & 3) * 8;
    #pragma unroll
    for (int t = 0; t < 2; t++) {
        const int row = w * 32 + t * 16 + srow;
        gload16(gbase + (size_t)row * ld + scol, &lds[w * 32 + t * 16][0]);
    }
}

// Compute one BK=64 step from staged A/B tiles (vt_gemm).
static __device__ __forceinline__ void mfma_step(
    const unsigned short (*Ash)[64], const unsigned short (*Bsh)[64],
    f32x4 acc[4][4], int wm, int wn, int lr, int lg)
{
    #pragma unroll
    for (int kk = 0; kk < 2; kk++) {
        short8 af[4], bf[4];
        #pragma unroll
        for (int m = 0; m < 4; m++)
            af[m] = *reinterpret_cast<const short8*>(&Ash[wm * 64 + m * 16 + lr][kk * 32 + lg * 8]);
        #pragma unroll
        for (int n = 0; n < 4; n++)
            bf[n] = *reinterpret_cast<const short8*>(&Bsh[wn * 64 + n * 16 + lr][kk * 32 + lg * 8]);
        #pragma unroll
        for (int m = 0; m < 4; m++)
            #pragma unroll
            for (int n = 0; n < 4; n++)
                acc[m][n] = __builtin_amdgcn_mfma_f32_16x16x32_bf16(af[m], bf[n], acc[m][n], 0, 0, 0);
    }
}

// Compute one BK=32 step from staged [128][32] A/B tiles (qk_gemm, pv_gemm).
static __device__ __forceinline__ void mfma_step32(
    const unsigned short (*Ash)[32], const unsigned short (*Bsh)[32],
    f32x4 acc[4][4], int wm, int wn, int lr, int lg)
{
    short8 af[4], bf[4];
    #pragma unroll
    for (int m = 0; m < 4; m++)
        af[m] = *reinterpret_cast<const short8*>(&Ash[wm * 64 + m * 16 + lr][lg * 8]);
    #pragma unroll
    for (int n = 0; n < 4; n++)
        bf[n] = *reinterpret_cast<const short8*>(&Bsh[wn * 64 + n * 16 + lr][lg * 8]);
    #pragma unroll
    for (int m = 0; m < 4; m++)
        #pragma unroll
        for (int n = 0; n < 4; n++)
            acc[m][n] = __builtin_amdgcn_mfma_f32_16x16x32_bf16(af[m], bf[n], acc[m][n], 0, 0, 0);
}

// Converts x (8192 blocks) and Wq/Wk/Wv (256 blocks each) fp32->bf16.
__global__ __launch_bounds__(256) void cvt_all(
    const float* __restrict__ x,
    const float* __restrict__ wq, const float* __restrict__ wk, const float* __restrict__ wv,
    unsigned short* __restrict__ xb,
    unsigned short* __restrict__ wqb, unsigned short* __restrict__ wkb,
    unsigned short* __restrict__ wvb)
{
    const int bid = blockIdx.x;
    const float* src; unsigned short* dst; int i;
    if (bid < 8192) { src = x; dst = xb; i = bid * 256 + threadIdx.x; }
    else {
        const int r = bid - 8192;
        const int m = r >> 8;
        src = (m == 0) ? wq : (m == 1) ? wk : wv;
        dst = (m == 0) ? wqb : (m == 1) ? wkb : wvb;
        i = (r & 255) * 256 + threadIdx.x;
    }
    float4 v = reinterpret_cast<const float4*>(src)[i];
    ushort4 o;
    o.x = f2bf(v.x); o.y = f2bf(v.y); o.z = f2bf(v.z); o.w = f2bf(v.w);
    reinterpret_cast<ushort4*>(dst)[i] = o;
}

// Fused Q,K projection: Q = x Wq^T + bq; K = x Wk^T + bk. BK=32, X staged once.
__global__ __launch_bounds__(256) void qk_proj(
    const unsigned short* __restrict__ X,
    const unsigned short* __restrict__ Wqb, const unsigned short* __restrict__ Wkb,
    const float* __restrict__ bq, const float* __restrict__ bk,
    unsigned short* __restrict__ Dq, unsigned short* __restrict__ Dk)
{
    __shared__ unsigned short smem[2][3][128][32];   // 48 KB

    const int m0 = blockIdx.x * 128;
    const int n0 = blockIdx.y * 128;

    const int tid  = threadIdx.x;
    const int lane = tid & 63;
    const int w    = tid >> 6;
    const int wm   = w >> 1, wn = w & 1;
    const int lr   = lane & 15, lg = lane >> 4;

    f32x4 accq[4][4], acck[4][4];
    #pragma unroll
    for (int m = 0; m < 4; m++)
        #pragma unroll
        for (int n = 0; n < 4; n++) {
            accq[m][n] = (f32x4){0.f, 0.f, 0.f, 0.f};
            acck[m][n] = (f32x4){0.f, 0.f, 0.f, 0.f};
        }

    stage32(&X[(size_t)m0 * DM], DM, smem[0][0], w, lane);
    stage32(&Wqb[(size_t)n0 * DM], DM, smem[0][1], w, lane);
    stage32(&Wkb[(size_t)n0 * DM], DM, smem[0][2], w, lane);
    __syncthreads();
    int cur = 0;
    for (int t = 0; t < 16; t++) {
        if (t < 15) {
            const int k0 = (t + 1) * 32;
            stage32(&X[(size_t)m0 * DM + k0], DM, smem[cur ^ 1][0], w, lane);
            stage32(&Wqb[(size_t)n0 * DM + k0], DM, smem[cur ^ 1][1], w, lane);
            stage32(&Wkb[(size_t)n0 * DM + k0], DM, smem[cur ^ 1][2], w, lane);
        }
        short8 af[4], bqf[4], bkf[4];
        #pragma unroll
        for (int m = 0; m < 4; m++)
            af[m] = *reinterpret_cast<const short8*>(&smem[cur][0][wm * 64 + m * 16 + lr][lg * 8]);
        #pragma unroll
        for (int n = 0; n < 4; n++) {
            bqf[n] = *reinterpret_cast<const short8*>(&smem[cur][1][wn * 64 + n * 16 + lr][lg * 8]);
            bkf[n] = *reinterpret_cast<const short8*>(&smem[cur][2][wn * 64 + n * 16 + lr][lg * 8]);
        }
        #pragma unroll
        for (int m = 0; m < 4; m++)
            #pragma unroll
            for (int n = 0; n < 4; n++) {
                accq[m][n] = __builtin_amdgcn_mfma_f32_16x16x32_bf16(af[m], bqf[n], accq[m][n], 0, 0, 0);
                acck[m][n] = __builtin_amdgcn_mfma_f32_16x16x32_bf16(af[m], bkf[n], acck[m][n], 0, 0, 0);
            }
        __syncthreads();
        cur ^= 1;
    }

    // Dual repacked epilogue: Q then K through the same Csh.
    unsigned short (*Csh)[128] = reinterpret_cast<unsigned short (*)[128]>(&smem[0][0][0][0]);
    #pragma unroll
    for (int n = 0; n < 4; n++) {
        int ct = wn * 64 + n * 16 + lr;
        float bcol = bq[n0 + ct];
        #pragma unroll
        for (int m = 0; m < 4; m++) {
            int rt = wm * 64 + m * 16 + lg * 4;
            #pragma unroll
            for (int j = 0; j < 4; j++) {
                int row = rt + j;
                Csh[row][ct ^ ((row & 7) << 3)] = f2bf(accq[m][n][j] + bcol);
            }
        }
    }
    __syncthreads();
    #pragma unroll
    for (int i = 0; i < 8; i++) {
        int chunk = i * 256 + tid;
        int row = chunk >> 4, cb = (chunk & 15) * 8;
        short8 vv = *reinterpret_cast<const short8*>(&Csh[row][cb ^ ((row & 7) << 3)]);
        *reinterpret_cast<short8*>(&Dq[(size_t)(m0 + row) * DM + n0 + cb]) = vv;
    }
    __syncthreads();
    #pragma unroll
    for (int n = 0; n < 4; n++) {
        int ct = wn * 64 + n * 16 + lr;
        float bcol = bk[n0 + ct];
        #pragma unroll
        for (int m = 0; m < 4; m++) {
            int rt = wm * 64 + m * 16 + lg * 4;
            #pragma unroll
            for (int j = 0; j < 4; j++) {
                int row = rt + j;
                Csh[row][ct ^ ((row & 7) << 3)] = f2bf(acck[m][n][j] + bcol);
            }
        }
    }
    __syncthreads();
    #pragma unroll
    for (int i = 0; i < 8; i++) {
        int chunk = i * 256 + tid;
        int row = chunk >> 4, cb = (chunk & 15) * 8;
        short8 vv = *reinterpret_cast<const short8*>(&Csh[row][cb ^ ((row & 7) << 3)]);
        *reinterpret_cast<short8*>(&Dk[(size_t)(m0 + row) * DM + n0 + cb]) = vv;
    }
}

// VT = Wv x^T + bv(per row): [512][16384], BK=64 2-phase.
__global__ __launch_bounds__(256) void vt_gemm(
    const unsigned short* __restrict__ X, const unsigned short* __restrict__ Wvb,
    const float* __restrict__ bv, unsigned short* __restrict__ Dvt)
{
    __shared__ unsigned short smem[2][2][128][64];

    const int m0 = blockIdx.y * 128;      // over DM=512
    const int n0 = blockIdx.x * 128;      // over 16384 tokens

    const int tid  = threadIdx.x;
    const int lane = tid & 63;
    const int w    = tid >> 6;
    const int wm   = w >> 1, wn = w & 1;
    const int lr   = lane & 15, lg = lane >> 4;

    f32x4 acc[4][4];
    #pragma unroll
    for (int m = 0; m < 4; m++)
        #pragma unroll
        for (int n = 0; n < 4; n++) acc[m][n] = (f32x4){0.f, 0.f, 0.f, 0.f};

    stage_tile(&Wvb[(size_t)m0 * DM], DM, smem[0][0], w, lane);
    stage_tile(&X[(size_t)n0 * DM], DM, smem[0][1], w, lane);
    __syncthreads();
    int cur = 0;
    for (int t = 0; t < 8; t++) {
        if (t < 7) {
            const int k0 = (t + 1) * 64;
            stage_tile(&Wvb[(size_t)m0 * DM + k0], DM, smem[cur ^ 1][0], w, lane);
            stage_tile(&X[(size_t)n0 * DM + k0], DM, smem[cur ^ 1][1], w, lane);
        }
        mfma_step(smem[cur][0], smem[cur][1], acc, wm, wn, lr, lg);
        __syncthreads();
        cur ^= 1;
    }

    unsigned short (*Csh)[128] = reinterpret_cast<unsigned short (*)[128]>(&smem[0][0][0][0]);
    #pragma unroll
    for (int n = 0; n < 4; n++) {
        int ct = wn * 64 + n * 16 + lr;
        #pragma unroll
        for (int m = 0; m < 4; m++) {
            int rt = wm * 64 + m * 16 + lg * 4;
            #pragma unroll
            for (int j = 0; j < 4; j++) {
                int row = rt + j;
                Csh[row][ct ^ ((row & 7) << 3)] = f2bf(acc[m][n][j] + bv[m0 + row]);
            }
        }
    }
    __syncthreads();
    #pragma unroll
    for (int i = 0; i < 8; i++) {
        int chunk = i * 256 + tid;
        int row = chunk >> 4, cb = (chunk & 15) * 8;
        short8 vv = *reinterpret_cast<const short8*>(&Csh[row][cb ^ ((row & 7) << 3)]);
        *reinterpret_cast<short8*>(&Dvt[(size_t)(m0 + row) * 16384 + n0 + cb]) = vv;
    }
}

// P tiles, exact lower triangle, all 8 batches. 1-D grid 1088:
// b = wgid & 7 (XCD-pinned batch), l = wgid >> 3.
// BK=32 2-phase dbuf, 32KB LDS (r15: 40.4us).
__global__ __launch_bounds__(256) void qk_gemm(
    const unsigned short* __restrict__ Qg, const unsigned short* __restrict__ Kg,
    const unsigned char* __restrict__ pad, unsigned short* __restrict__ Sp,
    float* __restrict__ partial)
{
    __shared__ unsigned short smem[2][2][128][32];   // 32 KB

    const int wgid = blockIdx.x;
    const int b = wgid & 7;
    const int l = wgid >> 3;
    int it = (int)((sqrtf(8.f * l + 1.f) - 1.f) * 0.5f);
    while ((it + 1) * (it + 2) / 2 <= l) ++it;
    while (it * (it + 1) / 2 > l) --it;
    const int jt = l - it * (it + 1) / 2;

    const unsigned short* __restrict__ A = Qg + (size_t)b * S_ * DM;
    const unsigned short* __restrict__ B = Kg + (size_t)b * S_ * DM;
    unsigned short* __restrict__ Sw = Sp + ((size_t)b * 136 + l) * 16384;
    const int m0 = it * 128, n0 = jt * 128;

    const int tid  = threadIdx.x;
    const int lane = tid & 63;
    const int w    = tid >> 6;
    const int wm   = w >> 1, wn = w & 1;
    const int lr   = lane & 15, lg = lane >> 4;

    f32x4 acc[4][4];
    #pragma unroll
    for (int m = 0; m < 4; m++)
        #pragma unroll
        for (int n = 0; n < 4; n++) acc[m][n] = (f32x4){0.f, 0.f, 0.f, 0.f};

    stage32(&A[(size_t)m0 * DM], DM, smem[0][0], w, lane);
    stage32(&B[(size_t)n0 * DM], DM, smem[0][1], w, lane);
    __syncthreads();
    int cur = 0;
    for (int t = 0; t < 16; t++) {
        if (t < 15) {
            const int k0 = (t + 1) * 32;
            stage32(&A[(size_t)m0 * DM + k0], DM, smem[cur ^ 1][0], w, lane);
            stage32(&B[(size_t)n0 * DM + k0], DM, smem[cur ^ 1][1], w, lane);
        }
        mfma_step32(smem[cur][0], smem[cur][1], acc, wm, wn, lr, lg);
        __syncthreads();
        cur ^= 1;
    }

    // epilogue: P = exp(s*scale) (masked -> 0), repack via 32KB Csh view,
    // 16B/lane stores + per-(row,jt) partial sums.
    unsigned short (*Csh)[128] = reinterpret_cast<unsigned short (*)[128]>(&smem[0][0][0][0]);
    #pragma unroll
    for (int n = 0; n < 4; n++) {
        int ct = wn * 64 + n * 16 + lr;
        int colg = n0 + ct;
        bool pd = pad[(size_t)b * S_ + colg] != 0;
        #pragma unroll
        for (int m = 0; m < 4; m++) {
            int rt = wm * 64 + m * 16 + lg * 4;
            #pragma unroll
            for (int j = 0; j < 4; j++) {
                int row = rt + j;
                float p = (pd || colg > m0 + row) ? 0.f : __expf(acc[m][n][j] * SCALE);
                Csh[row][ct ^ ((row & 7) << 3)] = f2bf(p);
            }
        }
    }
    __syncthreads();
    #pragma unroll
    for (int i = 0; i < 8; i++) {
        int chunk = i * 256 + tid;
        int row = chunk >> 4, cb = (chunk & 15) * 8;
        short8 vv = *reinterpret_cast<const short8*>(&Csh[row][cb ^ ((row & 7) << 3)]);
        *reinterpret_cast<short8*>(&Sw[(size_t)row * 128 + cb]) = vv;
        float s = 0.f;
        #pragma unroll
        for (int e = 0; e < 8; e++) s += bf2f((unsigned short)vv[e]);
        #pragma unroll
        for (int msk = 1; msk < 16; msk <<= 1) s += __shfl_xor(s, msk);
        if ((lane & 15) == 0)
            partial[((size_t)b * S_ + m0 + row) * 16 + jt] = s;
    }
}

// O[q][d] = (sum_{k<kmax} P[q][k] * VT[d][b*2048+k]) / l[q], fp32 out.
// 1-D grid 512: b = wgid & 7 (XCD-pinned), r = wgid >> 3 in [0,64).
// Complementary pairing: it = (r<32) ? 15-(r>>2) : (r>>2)-8; nb = r & 3.
// BK=32 2-phase dbuf, 32KB LDS (r15 qk transform applied).
__global__ __launch_bounds__(256) void pv_gemm(
    const unsigned short* __restrict__ Sp, const unsigned short* __restrict__ VT,
    const float* __restrict__ partial, float* __restrict__ Out)
{
    __shared__ unsigned short smem[2][2][128][32];   // 32 KB

    const int wgid = blockIdx.x;
    const int b  = wgid & 7;
    const int r  = wgid >> 3;
    const int it = (r < 32) ? (15 - (r >> 2)) : ((r >> 2) - 8);
    const int nb = r & 3;
    const int m0 = it * 128, n0 = nb * 128;
    const int nt = (it + 1) * 4;              // BK=32 steps
    const unsigned short* __restrict__ Abase =
        Sp + ((size_t)b * 136 + (size_t)it * (it + 1) / 2) * 16384;
    const size_t vtoff = (size_t)n0 * 16384 + (size_t)b * S_;

    const int tid  = threadIdx.x;
    const int lane = tid & 63;
    const int w    = tid >> 6;
    const int wm   = w >> 1, wn = w & 1;
    const int lr   = lane & 15, lg = lane >> 4;

    f32x4 acc[4][4];
    #pragma unroll
    for (int m = 0; m < 4; m++)
        #pragma unroll
        for (int n = 0; n < 4; n++) acc[m][n] = (f32x4){0.f, 0.f, 0.f, 0.f};

    stage32(Abase, 128, smem[0][0], w, lane);
    stage32(&VT[vtoff], 16384, smem[0][1], w, lane);
    __syncthreads();
    int cur = 0;
    for (int t = 0; t < nt; t++) {
        if (t + 1 < nt) {
            const int k0 = (t + 1) * 32;
            stage32(Abase + (size_t)(k0 >> 7) * 16384 + (k0 & 127), 128, smem[cur ^ 1][0], w, lane);
            stage32(&VT[vtoff + k0], 16384, smem[cur ^ 1][1], w, lane);
        }
        mfma_step32(smem[cur][0], smem[cur][1], acc, wm, wn, lr, lg);
        __syncthreads();
        cur ^= 1;
    }

    // per-row 1/l into LDS (threads 0..127), then normalize + store
    float* Lsh = reinterpret_cast<float*>(&smem[0][0][0][0]);
    if (tid < 128) {
        const float* pr = &partial[((size_t)b * S_ + m0 + tid) * 16];
        float s = 0.f;
        for (int j = 0; j <= it; j++) s += pr[j];
        Lsh[tid] = 1.f / s;
    }
    __syncthreads();

    #pragma unroll
    for (int n = 0; n < 4; n++) {
        int col = n0 + wn * 64 + n * 16 + lr;
        #pragma unroll
        for (int m = 0; m < 4; m++) {
            int rowb = wm * 64 + m * 16 + lg * 4;
            #pragma unroll
            for (int j = 0; j < 4; j++) {
                int row = rowb + j;
                float li = Lsh[row];
                Out[((size_t)(b * S_ + m0 + row)) * DM + col] = acc[m][n][j] * li;
            }
        }
    }
}

extern "C" void kernel_launch(void* const* d_in, const int* in_sizes, int n_in,
                              void* d_out, int out_size, void* d_ws, size_t ws_size,
                              hipStream_t stream) {
    const float* x  = (const float*)d_in[0];
    const unsigned char* pad = (const unsigned char*)d_in[1];
    const float* Wq = (const float*)d_in[2];
    const float* bq = (const float*)d_in[3];
    const float* Wk = (const float*)d_in[4];
    const float* bk = (const float*)d_in[5];
    const float* Wv = (const float*)d_in[6];
    const float* bv = (const float*)d_in[7];
    float* out = (float*)d_out;

    char* ws = (char*)d_ws;
    unsigned short* vtb     = (unsigned short*)(ws);
    float*          partial = (float*)(ws + 16777216);
    unsigned short* Spacked = (unsigned short*)(ws + 17825792);
    unsigned short* xb      = (unsigned short*)(ws + 17825792);  // overlaps Spacked
    unsigned short* wqb     = (unsigned short*)(ws + 53477376);
    unsigned short* wkb     = wqb + 262144;
    unsigned short* wvb     = wqb + 524288;

    // Q,K bf16 scratch in d_out (2 x 16,777,216 B; dead before pv writes)
    unsigned short* qb = (unsigned short*)d_out;
    unsigned short* kb = qb + 8388608;

    cvt_all<<<8960, 256, 0, stream>>>(x, Wq, Wk, Wv, xb, wqb, wkb, wvb);

    dim3 gp2(128, 4);
    qk_proj<<<gp2, 256, 0, stream>>>(xb, wqb, wkb, bq, bk, qb, kb);

    dim3 gv(128, 4);
    vt_gemm<<<gv, 256, 0, stream>>>(xb, wvb, bv, vtb);

    qk_gemm<<<1088, 256, 0, stream>>>(qb, kb, pad, Spacked, partial);

    pv_gemm<<<512, 256, 0, stream>>>(Spacked, vtb, partial, out);
}

// Round 18
// 123.129 us; speedup vs baseline: 1.3217x; 1.0348x over previous
//
#include <hip/hip_runtime.h>
#include <hip/hip_bf16.h>

// B=8, S=2048, D=512. 5 launches (r15 config, measured session best 123.3us):
//   cvt(x,W) -> qk_proj (fused Q&K projection, BK=32) -> vt_gemm (V^T) ->
//   qk (128x128, BK=32 2-phase dbuf 32KB -> 4-5 blocks/CU, packed lower-tri
//       P=exp + row sums) -> pv (complement-paired, BK=64 2-phase, 1/l, fp32).
// 16x16x32 bf16 MFMA, global_load_lds width-16, XCD batch-pinning (b=wgid&7).
// Round 18: revert r17's pv BK=32 (-14us: pv grid = 512 WGs = 2 blocks/CU --
// co-residency is GRID-limited there, so smaller LDS bought nothing and 2x
// barrier drains hurt). BK=32 lever requires grid >= ~4x CU count (qk: 1088).
//
// ws layout (peak 55,050,240 B < 68,681,728 proven):
//   vtb     @ 0          : V^T bf16 [512][16384]
//   partial @ 16777216   : fp32 [16384][16] per-(row, jt-tile) P sums
//   Spacked @ 17825792   : P bf16, 8 x 136 tiles x 128x128 (35,651,584)
//   xb      @ 17825792   : x bf16 (OVERLAPS Spacked; dead before qk writes)
//   wb      @ 53477376   : Wq/Wk/Wv bf16 (3 x 524288)
// d_out scratch: Q bf16 @ 0, K bf16 @ 16777216 (dead before pv overwrites).

typedef __attribute__((ext_vector_type(8))) short short8;
typedef __attribute__((ext_vector_type(4))) float f32x4;

#define S_    2048
#define DM    512
#define SCALE 0.04419417382415922f   // 1/sqrt(512)

static __device__ __forceinline__ unsigned short f2bf(float f) {
    __hip_bfloat16 h = __float2bfloat16(f);
    unsigned short u;
    __builtin_memcpy(&u, &h, sizeof(u));
    return u;
}
static __device__ __forceinline__ float bf2f(unsigned short u) {
    union { unsigned int i; float f; } c;
    c.i = ((unsigned int)u) << 16;
    return c.f;
}

static __device__ __forceinline__ void gload16(const void* g, void* l) {
    __builtin_amdgcn_global_load_lds(
        (const __attribute__((address_space(1))) void*)g,
        (__attribute__((address_space(3))) void*)l, 16, 0, 0);
}

// Stage a 128x64-short tile (row stride ld shorts) into linear LDS [128][64].
static __device__ __forceinline__ void stage_tile(
    const unsigned short* __restrict__ gbase, size_t ld,
    unsigned short (*lds)[64], int w, int lane)
{
    const int srow = lane >> 3;
    const int scol = (lane & 7) * 8;
    #pragma unroll
    for (int t = 0; t < 4; t++) {
        const int row = w * 32 + t * 8 + srow;
        gload16(gbase + (size_t)row * ld + scol, &lds[w * 32 + t * 8][0]);
    }
}

// Stage a 128x32-short tile into linear LDS [128][32] (2 gload_lds per wave).
static __device__ __forceinline__ void stage32(
    const unsigned short* __restrict__ gbase, size_t ld,
    unsigned short (*lds)[32], int w, int lane)
{
    const int srow = lane >> 2;
    const int scol = (lane & 3) * 8;
    #pragma unroll
    for (int t = 0; t < 2; t++) {
        const int row = w * 32 + t * 16 + srow;
        gload16(gbase + (size_t)row * ld + scol, &lds[w * 32 + t * 16][0]);
    }
}

// Compute one BK=64 step from staged A/B tiles (vt_gemm, pv_gemm).
static __device__ __forceinline__ void mfma_step(
    const unsigned short (*Ash)[64], const unsigned short (*Bsh)[64],
    f32x4 acc[4][4], int wm, int wn, int lr, int lg)
{
    #pragma unroll
    for (int kk = 0; kk < 2; kk++) {
        short8 af[4], bf[4];
        #pragma unroll
        for (int m = 0; m < 4; m++)
            af[m] = *reinterpret_cast<const short8*>(&Ash[wm * 64 + m * 16 + lr][kk * 32 + lg * 8]);
        #pragma unroll
        for (int n = 0; n < 4; n++)
            bf[n] = *reinterpret_cast<const short8*>(&Bsh[wn * 64 + n * 16 + lr][kk * 32 + lg * 8]);
        #pragma unroll
        for (int m = 0; m < 4; m++)
            #pragma unroll
            for (int n = 0; n < 4; n++)
                acc[m][n] = __builtin_amdgcn_mfma_f32_16x16x32_bf16(af[m], bf[n], acc[m][n], 0, 0, 0);
    }
}

// Compute one BK=32 step from staged [128][32] A/B tiles (qk_gemm).
static __device__ __forceinline__ void mfma_step32(
    const unsigned short (*Ash)[32], const unsigned short (*Bsh)[32],
    f32x4 acc[4][4], int wm, int wn, int lr, int lg)
{
    short8 af[4], bf[4];
    #pragma unroll
    for (int m = 0; m < 4; m++)
        af[m] = *reinterpret_cast<const short8*>(&Ash[wm * 64 + m * 16 + lr][lg * 8]);
    #pragma unroll
    for (int n = 0; n < 4; n++)
        bf[n] = *reinterpret_cast<const short8*>(&Bsh[wn * 64 + n * 16 + lr][lg * 8]);
    #pragma unroll
    for (int m = 0; m < 4; m++)
        #pragma unroll
        for (int n = 0; n < 4; n++)
            acc[m][n] = __builtin_amdgcn_mfma_f32_16x16x32_bf16(af[m], bf[n], acc[m][n], 0, 0, 0);
}

// Converts x (8192 blocks) and Wq/Wk/Wv (256 blocks each) fp32->bf16.
__global__ __launch_bounds__(256) void cvt_all(
    const float* __restrict__ x,
    const float* __restrict__ wq, const float* __restrict__ wk, const float* __restrict__ wv,
    unsigned short* __restrict__ xb,
    unsigned short* __restrict__ wqb, unsigned short* __restrict__ wkb,
    unsigned short* __restrict__ wvb)
{
    const int bid = blockIdx.x;
    const float* src; unsigned short* dst; int i;
    if (bid < 8192) { src = x; dst = xb; i = bid * 256 + threadIdx.x; }
    else {
        const int r = bid - 8192;
        const int m = r >> 8;
        src = (m == 0) ? wq : (m == 1) ? wk : wv;
        dst = (m == 0) ? wqb : (m == 1) ? wkb : wvb;
        i = (r & 255) * 256 + threadIdx.x;
    }
    float4 v = reinterpret_cast<const float4*>(src)[i];
    ushort4 o;
    o.x = f2bf(v.x); o.y = f2bf(v.y); o.z = f2bf(v.z); o.w = f2bf(v.w);
    reinterpret_cast<ushort4*>(dst)[i] = o;
}

// Fused Q,K projection: Q = x Wq^T + bq; K = x Wk^T + bk. BK=32, X staged once.
__global__ __launch_bounds__(256) void qk_proj(
    const unsigned short* __restrict__ X,
    const unsigned short* __restrict__ Wqb, const unsigned short* __restrict__ Wkb,
    const float* __restrict__ bq, const float* __restrict__ bk,
    unsigned short* __restrict__ Dq, unsigned short* __restrict__ Dk)
{
    __shared__ unsigned short smem[2][3][128][32];   // 48 KB

    const int m0 = blockIdx.x * 128;
    const int n0 = blockIdx.y * 128;

    const int tid  = threadIdx.x;
    const int lane = tid & 63;
    const int w    = tid >> 6;
    const int wm   = w >> 1, wn = w & 1;
    const int lr   = lane & 15, lg = lane >> 4;

    f32x4 accq[4][4], acck[4][4];
    #pragma unroll
    for (int m = 0; m < 4; m++)
        #pragma unroll
        for (int n = 0; n < 4; n++) {
            accq[m][n] = (f32x4){0.f, 0.f, 0.f, 0.f};
            acck[m][n] = (f32x4){0.f, 0.f, 0.f, 0.f};
        }

    stage32(&X[(size_t)m0 * DM], DM, smem[0][0], w, lane);
    stage32(&Wqb[(size_t)n0 * DM], DM, smem[0][1], w, lane);
    stage32(&Wkb[(size_t)n0 * DM], DM, smem[0][2], w, lane);
    __syncthreads();
    int cur = 0;
    for (int t = 0; t < 16; t++) {
        if (t < 15) {
            const int k0 = (t + 1) * 32;
            stage32(&X[(size_t)m0 * DM + k0], DM, smem[cur ^ 1][0], w, lane);
            stage32(&Wqb[(size_t)n0 * DM + k0], DM, smem[cur ^ 1][1], w, lane);
            stage32(&Wkb[(size_t)n0 * DM + k0], DM, smem[cur ^ 1][2], w, lane);
        }
        short8 af[4], bqf[4], bkf[4];
        #pragma unroll
        for (int m = 0; m < 4; m++)
            af[m] = *reinterpret_cast<const short8*>(&smem[cur][0][wm * 64 + m * 16 + lr][lg * 8]);
        #pragma unroll
        for (int n = 0; n < 4; n++) {
            bqf[n] = *reinterpret_cast<const short8*>(&smem[cur][1][wn * 64 + n * 16 + lr][lg * 8]);
            bkf[n] = *reinterpret_cast<const short8*>(&smem[cur][2][wn * 64 + n * 16 + lr][lg * 8]);
        }
        #pragma unroll
        for (int m = 0; m < 4; m++)
            #pragma unroll
            for (int n = 0; n < 4; n++) {
                accq[m][n] = __builtin_amdgcn_mfma_f32_16x16x32_bf16(af[m], bqf[n], accq[m][n], 0, 0, 0);
                acck[m][n] = __builtin_amdgcn_mfma_f32_16x16x32_bf16(af[m], bkf[n], acck[m][n], 0, 0, 0);
            }
        __syncthreads();
        cur ^= 1;
    }

    // Dual repacked epilogue: Q then K through the same Csh.
    unsigned short (*Csh)[128] = reinterpret_cast<unsigned short (*)[128]>(&smem[0][0][0][0]);
    #pragma unroll
    for (int n = 0; n < 4; n++) {
        int ct = wn * 64 + n * 16 + lr;
        float bcol = bq[n0 + ct];
        #pragma unroll
        for (int m = 0; m < 4; m++) {
            int rt = wm * 64 + m * 16 + lg * 4;
            #pragma unroll
            for (int j = 0; j < 4; j++) {
                int row = rt + j;
                Csh[row][ct ^ ((row & 7) << 3)] = f2bf(accq[m][n][j] + bcol);
            }
        }
    }
    __syncthreads();
    #pragma unroll
    for (int i = 0; i < 8; i++) {
        int chunk = i * 256 + tid;
        int row = chunk >> 4, cb = (chunk & 15) * 8;
        short8 vv = *reinterpret_cast<const short8*>(&Csh[row][cb ^ ((row & 7) << 3)]);
        *reinterpret_cast<short8*>(&Dq[(size_t)(m0 + row) * DM + n0 + cb]) = vv;
    }
    __syncthreads();
    #pragma unroll
    for (int n = 0; n < 4; n++) {
        int ct = wn * 64 + n * 16 + lr;
        float bcol = bk[n0 + ct];
        #pragma unroll
        for (int m = 0; m < 4; m++) {
            int rt = wm * 64 + m * 16 + lg * 4;
            #pragma unroll
            for (int j = 0; j < 4; j++) {
                int row = rt + j;
                Csh[row][ct ^ ((row & 7) << 3)] = f2bf(acck[m][n][j] + bcol);
            }
        }
    }
    __syncthreads();
    #pragma unroll
    for (int i = 0; i < 8; i++) {
        int chunk = i * 256 + tid;
        int row = chunk >> 4, cb = (chunk & 15) * 8;
        short8 vv = *reinterpret_cast<const short8*>(&Csh[row][cb ^ ((row & 7) << 3)]);
        *reinterpret_cast<short8*>(&Dk[(size_t)(m0 + row) * DM + n0 + cb]) = vv;
    }
}

// VT = Wv x^T + bv(per row): [512][16384], BK=64 2-phase.
__global__ __launch_bounds__(256) void vt_gemm(
    const unsigned short* __restrict__ X, const unsigned short* __restrict__ Wvb,
    const float* __restrict__ bv, unsigned short* __restrict__ Dvt)
{
    __shared__ unsigned short smem[2][2][128][64];

    const int m0 = blockIdx.y * 128;      // over DM=512
    const int n0 = blockIdx.x * 128;      // over 16384 tokens

    const int tid  = threadIdx.x;
    const int lane = tid & 63;
    const int w    = tid >> 6;
    const int wm   = w >> 1, wn = w & 1;
    const int lr   = lane & 15, lg = lane >> 4;

    f32x4 acc[4][4];
    #pragma unroll
    for (int m = 0; m < 4; m++)
        #pragma unroll
        for (int n = 0; n < 4; n++) acc[m][n] = (f32x4){0.f, 0.f, 0.f, 0.f};

    stage_tile(&Wvb[(size_t)m0 * DM], DM, smem[0][0], w, lane);
    stage_tile(&X[(size_t)n0 * DM], DM, smem[0][1], w, lane);
    __syncthreads();
    int cur = 0;
    for (int t = 0; t < 8; t++) {
        if (t < 7) {
            const int k0 = (t + 1) * 64;
            stage_tile(&Wvb[(size_t)m0 * DM + k0], DM, smem[cur ^ 1][0], w, lane);
            stage_tile(&X[(size_t)n0 * DM + k0], DM, smem[cur ^ 1][1], w, lane);
        }
        mfma_step(smem[cur][0], smem[cur][1], acc, wm, wn, lr, lg);
        __syncthreads();
        cur ^= 1;
    }

    unsigned short (*Csh)[128] = reinterpret_cast<unsigned short (*)[128]>(&smem[0][0][0][0]);
    #pragma unroll
    for (int n = 0; n < 4; n++) {
        int ct = wn * 64 + n * 16 + lr;
        #pragma unroll
        for (int m = 0; m < 4; m++) {
            int rt = wm * 64 + m * 16 + lg * 4;
            #pragma unroll
            for (int j = 0; j < 4; j++) {
                int row = rt + j;
                Csh[row][ct ^ ((row & 7) << 3)] = f2bf(acc[m][n][j] + bv[m0 + row]);
            }
        }
    }
    __syncthreads();
    #pragma unroll
    for (int i = 0; i < 8; i++) {
        int chunk = i * 256 + tid;
        int row = chunk >> 4, cb = (chunk & 15) * 8;
        short8 vv = *reinterpret_cast<const short8*>(&Csh[row][cb ^ ((row & 7) << 3)]);
        *reinterpret_cast<short8*>(&Dvt[(size_t)(m0 + row) * 16384 + n0 + cb]) = vv;
    }
}

// P tiles, exact lower triangle, all 8 batches. 1-D grid 1088:
// b = wgid & 7 (XCD-pinned batch), l = wgid >> 3.
// BK=32 2-phase dbuf, 32KB LDS -> 4-5 blocks/CU (r15: 40.4us, 463 TF).
__global__ __launch_bounds__(256) void qk_gemm(
    const unsigned short* __restrict__ Qg, const unsigned short* __restrict__ Kg,
    const unsigned char* __restrict__ pad, unsigned short* __restrict__ Sp,
    float* __restrict__ partial)
{
    __shared__ unsigned short smem[2][2][128][32];   // 32 KB

    const int wgid = blockIdx.x;
    const int b = wgid & 7;
    const int l = wgid >> 3;
    int it = (int)((sqrtf(8.f * l + 1.f) - 1.f) * 0.5f);
    while ((it + 1) * (it + 2) / 2 <= l) ++it;
    while (it * (it + 1) / 2 > l) --it;
    const int jt = l - it * (it + 1) / 2;

    const unsigned short* __restrict__ A = Qg + (size_t)b * S_ * DM;
    const unsigned short* __restrict__ B = Kg + (size_t)b * S_ * DM;
    unsigned short* __restrict__ Sw = Sp + ((size_t)b * 136 + l) * 16384;
    const int m0 = it * 128, n0 = jt * 128;

    const int tid  = threadIdx.x;
    const int lane = tid & 63;
    const int w    = tid >> 6;
    const int wm   = w >> 1, wn = w & 1;
    const int lr   = lane & 15, lg = lane >> 4;

    f32x4 acc[4][4];
    #pragma unroll
    for (int m = 0; m < 4; m++)
        #pragma unroll
        for (int n = 0; n < 4; n++) acc[m][n] = (f32x4){0.f, 0.f, 0.f, 0.f};

    stage32(&A[(size_t)m0 * DM], DM, smem[0][0], w, lane);
    stage32(&B[(size_t)n0 * DM], DM, smem[0][1], w, lane);
    __syncthreads();
    int cur = 0;
    for (int t = 0; t < 16; t++) {
        if (t < 15) {
            const int k0 = (t + 1) * 32;
            stage32(&A[(size_t)m0 * DM + k0], DM, smem[cur ^ 1][0], w, lane);
            stage32(&B[(size_t)n0 * DM + k0], DM, smem[cur ^ 1][1], w, lane);
        }
        mfma_step32(smem[cur][0], smem[cur][1], acc, wm, wn, lr, lg);
        __syncthreads();
        cur ^= 1;
    }

    // epilogue: P = exp(s*scale) (masked -> 0), repack via 32KB Csh view,
    // 16B/lane stores + per-(row,jt) partial sums.
    unsigned short (*Csh)[128] = reinterpret_cast<unsigned short (*)[128]>(&smem[0][0][0][0]);
    #pragma unroll
    for (int n = 0; n < 4; n++) {
        int ct = wn * 64 + n * 16 + lr;
        int colg = n0 + ct;
        bool pd = pad[(size_t)b * S_ + colg] != 0;
        #pragma unroll
        for (int m = 0; m < 4; m++) {
            int rt = wm * 64 + m * 16 + lg * 4;
            #pragma unroll
            for (int j = 0; j < 4; j++) {
                int row = rt + j;
                float p = (pd || colg > m0 + row) ? 0.f : __expf(acc[m][n][j] * SCALE);
                Csh[row][ct ^ ((row & 7) << 3)] = f2bf(p);
            }
        }
    }
    __syncthreads();
    #pragma unroll
    for (int i = 0; i < 8; i++) {
        int chunk = i * 256 + tid;
        int row = chunk >> 4, cb = (chunk & 15) * 8;
        short8 vv = *reinterpret_cast<const short8*>(&Csh[row][cb ^ ((row & 7) << 3)]);
        *reinterpret_cast<short8*>(&Sw[(size_t)row * 128 + cb]) = vv;
        float s = 0.f;
        #pragma unroll
        for (int e = 0; e < 8; e++) s += bf2f((unsigned short)vv[e]);
        #pragma unroll
        for (int msk = 1; msk < 16; msk <<= 1) s += __shfl_xor(s, msk);
        if ((lane & 15) == 0)
            partial[((size_t)b * S_ + m0 + row) * 16 + jt] = s;
    }
}

// O[q][d] = (sum_{k<kmax} P[q][k] * VT[d][b*2048+k]) / l[q], fp32 out.
// 1-D grid 512: b = wgid & 7 (XCD-pinned), r = wgid >> 3 in [0,64).
// Complementary pairing: it = (r<32) ? 15-(r>>2) : (r>>2)-8; nb = r & 3.
// BK=64 2-phase dbuf (512-WG grid caps co-residency at 2/CU; BK=32 hurts).
__global__ __launch_bounds__(256) void pv_gemm(
    const unsigned short* __restrict__ Sp, const unsigned short* __restrict__ VT,
    const float* __restrict__ partial, float* __restrict__ Out)
{
    __shared__ unsigned short smem[2][2][128][64];

    const int wgid = blockIdx.x;
    const int b  = wgid & 7;
    const int r  = wgid >> 3;
    const int it = (r < 32) ? (15 - (r >> 2)) : ((r >> 2) - 8);
    const int nb = r & 3;
    const int m0 = it * 128, n0 = nb * 128;
    const int nt = (it + 1) * 2;              // BK=64 steps
    const unsigned short* __restrict__ Abase =
        Sp + ((size_t)b * 136 + (size_t)it * (it + 1) / 2) * 16384;

    const int tid  = threadIdx.x;
    const int lane = tid & 63;
    const int w    = tid >> 6;
    const int wm   = w >> 1, wn = w & 1;
    const int lr   = lane & 15, lg = lane >> 4;

    f32x4 acc[4][4];
    #pragma unroll
    for (int m = 0; m < 4; m++)
        #pragma unroll
        for (int n = 0; n < 4; n++) acc[m][n] = (f32x4){0.f, 0.f, 0.f, 0.f};

    stage_tile(Abase, 128, smem[0][0], w, lane);
    stage_tile(&VT[(size_t)n0 * 16384 + (size_t)b * S_], 16384, smem[0][1], w, lane);
    __syncthreads();
    int cur = 0;
    for (int t = 0; t < nt; t++) {
        if (t + 1 < nt) {
            const int k0 = (t + 1) * 64;
            stage_tile(Abase + (size_t)(k0 >> 7) * 16384 + (k0 & 127), 128, smem[cur ^ 1][0], w, lane);
            stage_tile(&VT[(size_t)n0 * 16384 + (size_t)b * S_ + k0], 16384, smem[cur ^ 1][1], w, lane);
        }
        mfma_step(smem[cur][0], smem[cur][1], acc, wm, wn, lr, lg);
        __syncthreads();
        cur ^= 1;
    }

    // per-row 1/l into LDS (threads 0..127), then normalize + store
    float* Lsh = reinterpret_cast<float*>(&smem[0][0][0][0]);
    if (tid < 128) {
        const float* pr = &partial[((size_t)b * S_ + m0 + tid) * 16];
        float s = 0.f;
        for (int j = 0; j <= it; j++) s += pr[j];
        Lsh[tid] = 1.f / s;
    }
    __syncthreads();

    #pragma unroll
    for (int n = 0; n < 4; n++) {
        int col = n0 + wn * 64 + n * 16 + lr;
        #pragma unroll
        for (int m = 0; m < 4; m++) {
            int rowb = wm * 64 + m * 16 + lg * 4;
            #pragma unroll
            for (int j = 0; j < 4; j++) {
                int row = rowb + j;
                float li = Lsh[row];
                Out[((size_t)(b * S_ + m0 + row)) * DM + col] = acc[m][n][j] * li;
            }
        }
    }
}

extern "C" void kernel_launch(void* const* d_in, const int* in_sizes, int n_in,
                              void* d_out, int out_size, void* d_ws, size_t ws_size,
                              hipStream_t stream) {
    const float* x  = (const float*)d_in[0];
    const unsigned char* pad = (const unsigned char*)d_in[1];
    const float* Wq = (const float*)d_in[2];
    const float* bq = (const float*)d_in[3];
    const float* Wk = (const float*)d_in[4];
    const float* bk = (const float*)d_in[5];
    const float* Wv = (const float*)d_in[6];
    const float* bv = (const float*)d_in[7];
    float* out = (float*)d_out;

    char* ws = (char*)d_ws;
    unsigned short* vtb     = (unsigned short*)(ws);
    float*          partial = (float*)(ws + 16777216);
    unsigned short* Spacked = (unsigned short*)(ws + 17825792);
    unsigned short* xb      = (unsigned short*)(ws + 17825792);  // overlaps Spacked
    unsigned short* wqb     = (unsigned short*)(ws + 53477376);
    unsigned short* wkb     = wqb + 262144;
    unsigned short* wvb     = wqb + 524288;

    // Q,K bf16 scratch in d_out (2 x 16,777,216 B; dead before pv writes)
    unsigned short* qb = (unsigned short*)d_out;
    unsigned short* kb = qb + 8388608;

    cvt_all<<<8960, 256, 0, stream>>>(x, Wq, Wk, Wv, xb, wqb, wkb, wvb);

    dim3 gp2(128, 4);
    qk_proj<<<gp2, 256, 0, stream>>>(xb, wqb, wkb, bq, bk, qb, kb);

    dim3 gv(128, 4);
    vt_gemm<<<gv, 256, 0, stream>>>(xb, wvb, bv, vtb);

    qk_gemm<<<1088, 256, 0, stream>>>(qb, kb, pad, Spacked, partial);

    pv_gemm<<<512, 256, 0, stream>>>(Spacked, vtb, partial, out);
}